// Round 8
// baseline (483.530 us; speedup 1.0000x reference)
//
#include <hip/hip_runtime.h>
#include <hip/hip_bf16.h>

// Linear: C[M,N] = A[M,K] @ W[N,K]^T + bias[N]. fp32 in/out (harness maps fp16
// reference -> fp32 buffers), bf16 MFMA compute (2% threshold).
//
// Round 15: r7 (213.5 us) is LDS-PIPE-bound, not MFMA-bound: true matrix-pipe
// busy ~16% (79k of 512k cyc/CU; the 64% "MfmaUtil" is the gfx94x fallback
// formula not dividing by 4 SIMDs). LDS moved 72 KB/block-step (stage 24 +
// read 48; every byte written once, read by 2 waves) -> 137 us floor at
// 112 B/cyc. Cut: W fragments are PER-LANE-PRIVATE (each lane's 16 B chunk
// feeds only its own MFMA operand) -> W skips LDS entirely, loaded straight
// to registers via global_load_dwordx4 (swizzle is an address XOR on read; a
// wave still covers 16 full rows = 1 KB contiguous per instr, L2-resident
// under the rect swizzle). LDS now carries A only: 48 KB/step (-33%), floor
// 91 us. Freed LDS -> ring-4 x 16 KB (64 KB/block, 128 KB/CU), unroll-4
// static slots. W double-buffered in regs (2x16 VGPR, 1-step cover >= L2
// latency); A 2-step cover. Waits by pool enumeration: vmcnt(8) @ j=0,
// vmcnt(4) steady, vmcnt(0) last two. Reg budget ~124 VGPR + 128 AGPR ~= 252
// <= 256 -> 2 blocks/CU preserved (falsifier: Occupancy ~10% => blown).
// Epilogue/fragment math byte-identical to r7 (verified, absmax 0.0625).

typedef unsigned short u16;
typedef unsigned int u32;
typedef __bf16 bf16x8 __attribute__((ext_vector_type(8)));
typedef float f32x4 __attribute__((ext_vector_type(4)));
typedef u32 u32x4 __attribute__((ext_vector_type(4)));

#define M_DIM 8192
#define N_DIM 4096
#define K_DIM 4096

#define NT 128                          // 32-k K-steps
#define BLK_ELEMS 4096                  // 128 rows x 32 k per packed block
#define SLOT_ELEMS 8192                 // ring slot: A0 + A1 blocks (16 KB)

#define A_CHUNKS ((M_DIM / 128) * NT * 128 * 4)   // 4,194,304 16B chunks
#define W_CHUNKS ((N_DIM / 128) * NT * 128 * 4)   // 2,097,152
#define A_PACK_BYTES ((size_t)A_CHUNKS * 16)      // 64 MiB
#define W_PACK_BYTES ((size_t)W_CHUNKS * 16)      // 32 MiB

// pack two fp32 -> (bf16(hi)<<16)|bf16(lo) by byte-perm truncation
__device__ __forceinline__ u32 pack2bf(float lo, float hi) {
    return __builtin_amdgcn_perm(__float_as_uint(hi), __float_as_uint(lo),
                                 0x07060302u);
}

__device__ __forceinline__ void g2l16(const u16* g, __bf16* l) {
    __builtin_amdgcn_global_load_lds((__attribute__((address_space(1))) void*)g,
                                     (__attribute__((address_space(3))) void*)l,
                                     16, 0, 0);
}

// ---------------- Phase 1: convert + block-pack + swizzle (r5 verbatim) -----
// Packed layout: [panel][kstep][row][cp], 16B chunk cp at row r holds source
// chunk c = cp ^ ((r>>1)&3). One thread per chunk; coalesced reads, linear
// writes (1 KiB/wave).
__global__ __launch_bounds__(256) void pack_bf16_kernel(
    const float* __restrict__ A, const float* __restrict__ W,
    u32x4* __restrict__ aP, u32x4* __restrict__ wP)
{
    int gid = blockIdx.x * 256 + threadIdx.x;
    const float* src;
    u32x4* dst;
    int id;
    if (gid < A_CHUNKS) { src = A; dst = aP; id = gid; }
    else                { src = W; dst = wP; id = gid - A_CHUNKS; }

    const int cp  = id & 3;
    const int row = (id >> 2) & 127;
    const int j   = (id >> 9) & 127;          // k-step
    const int mp  = id >> 16;                 // 128-row panel
    const int c   = cp ^ ((row >> 1) & 3);    // source chunk

    const float* p = src + (size_t)(mp * 128 + row) * K_DIM + j * 32 + c * 8;
    f32x4 v0 = __builtin_nontemporal_load((const f32x4*)(p));
    f32x4 v1 = __builtin_nontemporal_load((const f32x4*)(p + 4));
    dst[id] = u32x4{pack2bf(v0[0], v0[1]), pack2bf(v0[2], v0[3]),
                    pack2bf(v1[0], v1[1]), pack2bf(v1[2], v1[3])};
}

// ---------------- Phase 2: 256x128 A-ring-4 + W-in-regs GEMM ---------------
// 256 thr / 4 waves (2M x 2N); wave tile 128x64 (acc[8][4] AGPR). LDS carries
// A only: ring-4 slots of one 32-k K-step (A blocks {2bm, 2bm+1}, 16 KB).
// W fragments are lane-private 16 B chunks -> global_load_dwordx4 directly
// into bfr regs, double-buffered. stage A(j+3) + load W(j+1) during step j.
__global__ __launch_bounds__(256, 2) void gemm_flatw_ring4_kernel(
    const u16* __restrict__ aP,      // packed A blocks (128x32, swizzled)
    const u16* __restrict__ wP,      // packed W blocks (128x32, swizzled)
    const float* __restrict__ bias,  // [N] fp32
    float* __restrict__ C)           // [M, N] fp32
{
    __shared__ __attribute__((aligned(16))) __bf16 ring[4][SLOT_ELEMS];

    const int tid  = threadIdx.x;
    const int lane = tid & 63;
    const int wave = tid >> 6;        // 0..3
    const int quad = lane >> 4;
    const int l16  = lane & 15;
    const int wm   = wave >> 1;       // 0..1 (128-row M half)
    const int wn   = wave & 1;        // 0..1 (64-col N half)

    // XCD-rect swizzle (r7, verified): 1024 blocks -> 8 rects of 16bm x 8bn;
    // per-XCD W working set 4 MB ~= L2.
    const int bid = blockIdx.x;
    const int x   = bid & 7;
    const int s   = bid >> 3;
    const int bm  = (x >> 2) * 16 + (s >> 3);   // 0..31 (256-row A pair)
    const int bn  = (x & 3) * 8 + (s & 7);      // 0..31 (128-row W panel)

    const u16* aB0 = aP + (size_t)(bm * 2    ) * NT * BLK_ELEMS;
    const u16* aB1 = aP + (size_t)(bm * 2 + 1) * NT * BLK_ELEMS;

    // per-lane W pointer: row = wn*64 + nb*16 + l16, chunk = quad^((l16>>1)&3)
    // (swizzle bits depend only on l16). One global_load_dwordx4 per nb; a
    // wave covers 16 complete rows = 1 KB contiguous per instruction.
    const int cpq = (quad ^ ((l16 >> 1) & 3)) * 8;
    const u16* wLane = wP + (size_t)bn * NT * BLK_ELEMS
                     + (wn * 64 + l16) * 32 + cpq;

    auto stageA = [&](int t, __bf16* sl) {
        const size_t o = (size_t)t * BLK_ELEMS + tid * 8;
        g2l16(aB0 + o,        sl + tid * 8);
        g2l16(aB0 + o + 2048, sl + 2048 + tid * 8);
        g2l16(aB1 + o,        sl + 4096 + tid * 8);
        g2l16(aB1 + o + 2048, sl + 6144 + tid * 8);
    };
    auto loadW = [&](int t, bf16x8 (&dst)[4]) {
        const u16* p = wLane + (size_t)t * BLK_ELEMS;
#pragma unroll
        for (int nb = 0; nb < 4; ++nb)
            dst[nb] = *(const bf16x8*)(p + nb * 512);
    };

    f32x4 acc[8][4];
#pragma unroll
    for (int i = 0; i < 8; ++i)
#pragma unroll
        for (int j = 0; j < 4; ++j)
            acc[i][j] = f32x4{0.f, 0.f, 0.f, 0.f};

    const int aOff = wm * 4096 + l16 * 32 + cpq;   // + rb*512 (16 rows)

    bf16x8 bfrA[4], bfrB[4];

    // prologue: W(0) first (issue order matters for vmcnt pool), then A(0..2)
    loadW(0, bfrA);
    stageA(0, ring[0]);
    stageA(1, ring[1]);
    stageA(2, ring[2]);

    // step j: read slot j%4, stage slot (j+3)%4, use bfr[j%2], load bfr[(j+1)%2]
    auto step = [&](int j, __bf16* rd, __bf16* stg,
                    bf16x8 (&use)[4], bf16x8 (&nxt)[4]) {
        // pool at wait: [A(j+1), W(j), A(j+2)] -> retire 8, keep newest 4.
        if (j == 0)           asm volatile("s_waitcnt vmcnt(8)" ::: "memory");
        else if (j >= NT - 2) asm volatile("s_waitcnt vmcnt(0)" ::: "memory");
        else                  asm volatile("s_waitcnt vmcnt(4)" ::: "memory");
        __builtin_amdgcn_s_barrier();
        asm volatile("" ::: "memory");   // pin issues after barrier

        if (j + 1 < NT) loadW(j + 1, nxt);     // W first
        if (j + 3 < NT) stageA(j + 3, stg);    // then A (pool order)

        bf16x8 af[8];
#pragma unroll
        for (int rb = 0; rb < 8; ++rb)
            af[rb] = *(const bf16x8*)&rd[aOff + rb * 512];

        __builtin_amdgcn_s_setprio(1);
#pragma unroll
        for (int rb = 0; rb < 8; ++rb)
#pragma unroll
            for (int nb = 0; nb < 4; ++nb)
                acc[rb][nb] = __builtin_amdgcn_mfma_f32_16x16x32_bf16(
                    af[rb], use[nb], acc[rb][nb], 0, 0, 0);
        __builtin_amdgcn_s_setprio(0);
    };

    for (int jb = 0; jb < NT; jb += 4) {       // static slots & W buffers
        step(jb + 0, ring[0], ring[3], bfrA, bfrB);
        step(jb + 1, ring[1], ring[0], bfrB, bfrA);
        step(jb + 2, ring[2], ring[1], bfrA, bfrB);
        step(jb + 3, ring[3], ring[2], bfrB, bfrA);
    }

    // epilogue: C/D layout col = lane&15, row = quad*4 + reg; fp32 out + bias
    const int colBase = bn * 128 + wn * 64 + l16;
    const int rowBase = bm * 256 + wm * 128 + quad * 4;
#pragma unroll
    for (int nb = 0; nb < 4; ++nb) {
        const int col = colBase + nb * 16;
        const float bv = bias[col];
#pragma unroll
        for (int rb = 0; rb < 8; ++rb) {
            const int row = rowBase + rb * 16;
#pragma unroll
            for (int r = 0; r < 4; ++r)
                C[(size_t)(row + r) * N_DIM + col] = acc[rb][nb][r] + bv;
        }
    }
}

// ---------------- Fallback (round-3 kernel, ws too small) ----------------
__global__ __launch_bounds__(256, 2) void linear_f32_bf16mfma_kernel(
    const float* __restrict__ A, const float* __restrict__ W,
    const float* __restrict__ bias, float* __restrict__ C)
{
    __shared__ __attribute__((aligned(16))) __bf16 sA[128 * 64];
    __shared__ __attribute__((aligned(16))) __bf16 sB[128 * 64];

    const int tid  = threadIdx.x;
    const int lane = tid & 63;
    const int wave = tid >> 6;
    const int quad = lane >> 4;
    const int l16  = lane & 15;
    const int wm   = wave >> 1;
    const int wn   = wave & 1;
    const int bn = blockIdx.x;
    const int bm = blockIdx.y;
    const int srow = tid >> 3;
    const int scol = (tid & 7) * 8;

    const float* aBase = A + (size_t)(bm * 128 + srow) * K_DIM + scol;
    const float* bBase = W + (size_t)(bn * 128 + srow) * K_DIM + scol;

    f32x4 acc[4][4];
#pragma unroll
    for (int i = 0; i < 4; ++i)
#pragma unroll
        for (int j = 0; j < 4; ++j)
            acc[i][j] = f32x4{0.f, 0.f, 0.f, 0.f};

    const int aRow = wm * 64 + l16;
    const int bRow = wn * 64 + l16;
    const int kOff = quad * 8;

    for (int k0 = 0; k0 < K_DIM; k0 += 64) {
        f32x4 ga[4][2], gb[4][2];
#pragma unroll
        for (int it = 0; it < 4; ++it) {
            const float* pa = aBase + (size_t)(it * 32) * K_DIM + k0;
            const float* pb = bBase + (size_t)(it * 32) * K_DIM + k0;
            ga[it][0] = *(const f32x4*)(pa);
            ga[it][1] = *(const f32x4*)(pa + 4);
            gb[it][0] = *(const f32x4*)(pb);
            gb[it][1] = *(const f32x4*)(pb + 4);
        }
        u32x4 wa[4], wb[4];
#pragma unroll
        for (int it = 0; it < 4; ++it) {
            wa[it] = u32x4{pack2bf(ga[it][0][0], ga[it][0][1]),
                           pack2bf(ga[it][0][2], ga[it][0][3]),
                           pack2bf(ga[it][1][0], ga[it][1][1]),
                           pack2bf(ga[it][1][2], ga[it][1][3])};
            wb[it] = u32x4{pack2bf(gb[it][0][0], gb[it][0][1]),
                           pack2bf(gb[it][0][2], gb[it][0][3]),
                           pack2bf(gb[it][1][0], gb[it][1][1]),
                           pack2bf(gb[it][1][2], gb[it][1][3])};
        }
        __syncthreads();
#pragma unroll
        for (int it = 0; it < 4; ++it) {
            *(u32x4*)&sA[tid * 8 + it * 2048] = wa[it];
            *(u32x4*)&sB[tid * 8 + it * 2048] = wb[it];
        }
        __syncthreads();
#pragma unroll
        for (int ks = 0; ks < 64; ks += 32) {
            bf16x8 af[4], bfr[4];
#pragma unroll
            for (int mi = 0; mi < 4; ++mi)
                af[mi] = *(const bf16x8*)&sA[(aRow + mi * 16) * 64 + ks + kOff];
#pragma unroll
            for (int ni = 0; ni < 4; ++ni)
                bfr[ni] = *(const bf16x8*)&sB[(bRow + ni * 16) * 64 + ks + kOff];
#pragma unroll
            for (int mi = 0; mi < 4; ++mi)
#pragma unroll
                for (int ni = 0; ni < 4; ++ni)
                    acc[mi][ni] = __builtin_amdgcn_mfma_f32_16x16x32_bf16(
                        af[mi], bfr[ni], acc[mi][ni], 0, 0, 0);
        }
    }
    const int colBase = bn * 128 + wn * 64 + l16;
    const int rowBase = bm * 128 + wm * 64 + quad * 4;
#pragma unroll
    for (int ni = 0; ni < 4; ++ni) {
        const int col = colBase + ni * 16;
        const float bv = bias[col];
#pragma unroll
        for (int mi = 0; mi < 4; ++mi) {
            const int row = rowBase + mi * 16;
#pragma unroll
            for (int r = 0; r < 4; ++r)
                C[(size_t)(row + r) * N_DIM + col] = acc[mi][ni][r] + bv;
        }
    }
}

extern "C" void kernel_launch(void* const* d_in, const int* in_sizes, int n_in,
                              void* d_out, int out_size, void* d_ws, size_t ws_size,
                              hipStream_t stream) {
    const float* x = (const float*)d_in[0];   // [8192, 4096]
    const float* w = (const float*)d_in[1];   // [4096, 4096]
    const float* b = (const float*)d_in[2];   // [4096]
    float* out = (float*)d_out;

    if (ws_size >= A_PACK_BYTES + W_PACK_BYTES) {
        u32x4* aP = (u32x4*)d_ws;
        u32x4* wP = (u32x4*)((char*)d_ws + A_PACK_BYTES);
        const int total_chunks = A_CHUNKS + W_CHUNKS;
        pack_bf16_kernel<<<total_chunks / 256, 256, 0, stream>>>(x, w, aP, wP);
        gemm_flatw_ring4_kernel<<<dim3(1024), 256, 0, stream>>>(
            (const u16*)aP, (const u16*)wP, b, out);
    } else {
        dim3 grid(N_DIM / 128, M_DIM / 128);
        linear_f32_bf16mfma_kernel<<<grid, 256, 0, stream>>>(x, w, b, out);
    }
}